// Round 4
// baseline (278.755 us; speedup 1.0000x reference)
//
#include <hip/hip_runtime.h>

#define B_ 4
#define C_ 128
#define N_ 4096
#define LOG2E 1.44269504088896340736f

typedef __bf16 bf16x8 __attribute__((ext_vector_type(8)));
typedef float  f32x16 __attribute__((ext_vector_type(16)));
typedef int    i32x4  __attribute__((ext_vector_type(4)));
typedef int    i32x2  __attribute__((ext_vector_type(2)));

static __device__ __forceinline__ unsigned int bfbits(float f) {
    unsigned int u = __float_as_uint(f);
    u += 0x7FFFu + ((u >> 16) & 1u);   // round-to-nearest-even
    return u >> 16;
}
static __device__ __forceinline__ int pk2(float lo, float hi) {
    return (int)(bfbits(lo) | (bfbits(hi) << 16));
}
static __device__ __forceinline__ float bf2f(unsigned short u) {
    return __uint_as_float((unsigned int)u << 16);
}

// ---------------- projection: q/k/v = W @ x + b (1x1 conv) -------------
// qT,kT stored [B][N][C] bf16 (q scaled by log2e); v stored [B][C][N] bf16.
__global__ __launch_bounds__(256) void proj_kernel(
    const float* __restrict__ x,
    const float* __restrict__ Wq, const float* __restrict__ bq,
    const float* __restrict__ Wk, const float* __restrict__ bk,
    const float* __restrict__ Wv, const float* __restrict__ bv,
    unsigned short* __restrict__ qT, unsigned short* __restrict__ kTt,
    unsigned short* __restrict__ vMat)
{
    __shared__ __align__(16) char wlds[32768];   // W bf16, swizzled rows

    const int tid  = threadIdx.x;
    const int wave = tid >> 6;
    const int lane = tid & 63;
    const int col  = lane & 31;
    const int h    = lane >> 5;

    const int jw  = blockIdx.x * 4 + wave;   // 0..1535 = mat*512 + b*128 + nb
    const int mat = jw >> 9;                 // uniform per WG (bid>>7)
    const int rem = jw & 511;
    const int b   = rem >> 7;
    const int nb  = rem & 127;
    const int n   = nb * 32 + col;

    const float* W    = (mat == 0) ? Wq : (mat == 1) ? Wk : Wv;
    const float* bias = (mat == 0) ? bq : (mat == 1) ? bk : bv;
    const float  scale = (mat == 0) ? LOG2E : 1.0f;

    #pragma unroll
    for (int k = 0; k < 16; ++k) {
        const int q = tid + k * 256;          // quad index, 4 floats each
        const int o = q >> 5;
        const int cb8 = (q & 31) * 8;         // byte offset of 4 bf16
        float4 w = *((const float4*)W + q);
        i32x2 d;
        d[0] = pk2(w.x * scale, w.y * scale);
        d[1] = pk2(w.z * scale, w.w * scale);
        *(i32x2*)(wlds + o * 256 + (cb8 ^ ((o & 7) << 4))) = d;
    }
    __syncthreads();

    bf16x8 xf[8];
    const float* xcol = x + (size_t)b * C_ * N_ + n;
    #pragma unroll
    for (int ch = 0; ch < 8; ++ch) {
        const int c0 = ch * 16 + 8 * h;
        i32x4 r;
        r[0] = pk2(xcol[(size_t)(c0 + 0) * N_], xcol[(size_t)(c0 + 1) * N_]);
        r[1] = pk2(xcol[(size_t)(c0 + 2) * N_], xcol[(size_t)(c0 + 3) * N_]);
        r[2] = pk2(xcol[(size_t)(c0 + 4) * N_], xcol[(size_t)(c0 + 5) * N_]);
        r[3] = pk2(xcol[(size_t)(c0 + 6) * N_], xcol[(size_t)(c0 + 7) * N_]);
        xf[ch] = __builtin_bit_cast(bf16x8, r);
    }

    f32x16 acc[4];
    #pragma unroll
    for (int ob = 0; ob < 4; ++ob)
        #pragma unroll
        for (int rr = 0; rr < 16; ++rr) acc[ob][rr] = 0.0f;

    const int swzw = (col & 7) << 4;
    #pragma unroll
    for (int ch = 0; ch < 8; ++ch) {
        #pragma unroll
        for (int ob = 0; ob < 4; ++ob) {
            const char* wrow = wlds + (ob * 32 + col) * 256;
            bf16x8 wf = __builtin_bit_cast(bf16x8,
                *(const i32x4*)(wrow + ((ch * 32 + 16 * h) ^ swzw)));
            acc[ob] = __builtin_amdgcn_mfma_f32_32x32x16_bf16(
                wf, xf[ch], acc[ob], 0, 0, 0);
        }
    }

    if (mat < 2) {
        unsigned short* dst = ((mat == 0) ? qT : kTt) + (size_t)(b * N_ + n) * C_;
        #pragma unroll
        for (int ob = 0; ob < 4; ++ob) {
            #pragma unroll
            for (int qd = 0; qd < 4; ++qd) {
                const int obase = ob * 32 + 8 * qd + 4 * h;
                const float f0 = acc[ob][4 * qd + 0] + bias[obase + 0] * scale;
                const float f1 = acc[ob][4 * qd + 1] + bias[obase + 1] * scale;
                const float f2 = acc[ob][4 * qd + 2] + bias[obase + 2] * scale;
                const float f3 = acc[ob][4 * qd + 3] + bias[obase + 3] * scale;
                i32x2 st; st[0] = pk2(f0, f1); st[1] = pk2(f2, f3);
                *(i32x2*)(dst + obase) = st;
            }
        }
    } else {
        unsigned short* dst = vMat + (size_t)b * C_ * N_ + n;
        #pragma unroll
        for (int ob = 0; ob < 4; ++ob) {
            #pragma unroll
            for (int rr = 0; rr < 16; ++rr) {
                const int o = ob * 32 + (rr & 3) + 8 * (rr >> 2) + 4 * h;
                dst[(size_t)o * N_] = (unsigned short)bfbits(acc[ob][rr] + bias[o]);
            }
        }
    }
}

// ---------------- flash attention over HALF the keys -------------------
// 512 WGs x 512 thr (2 WGs/CU). 8 waves = 2 q-blocks(32q) x 4 splits(512k).
// Writes un-normalized partial O (bf16) + per-query (M,L) to global.
__global__ __launch_bounds__(512, 4) void attn_half_kernel(
    const unsigned short* __restrict__ qT,
    const unsigned short* __restrict__ kTt,
    const unsigned short* __restrict__ vMat,
    unsigned short* __restrict__ pO,  // [2][B][C][N] bf16
    float2* __restrict__ mlG)         // [2][B][N] (M, L)
{
    __shared__ __align__(16) char smem[65536];

    const int tid  = threadIdx.x;
    const int wave = tid >> 6;
    const int lane = tid & 63;
    const int l31  = lane & 31;
    const int h    = lane >> 5;
    const int s    = wave >> 1;        // key split 0..3 (within half)
    const int qb   = wave & 1;         // q block within WG

    const int Wg = blockIdx.x;
    const int hf = Wg & 1;                         // key half 0/1
    const int b  = (Wg >> 1) & 3;
    const int qg = Wg >> 3;                        // 0..63
    const int i0 = qg * 64 + qb * 32;

    char* kbuf = smem + s * 16384;     // K 8KB | V 8KB per split
    char* vbuf = kbuf + 8192;

    // Q fragments: element e of chunk ch <-> c = ch*16 + 8h + e
    bf16x8 qf[8];
    {
        const unsigned short* qrow = qT + (size_t)(b * N_ + i0 + l31) * C_;
        #pragma unroll
        for (int ch = 0; ch < 8; ++ch)
            qf[ch] = __builtin_bit_cast(bf16x8, *(const i32x4*)(qrow + ch * 16 + 8 * h));
    }

    f32x16 accO[4];
    #pragma unroll
    for (int cb = 0; cb < 4; ++cb)
        #pragma unroll
        for (int rr = 0; rr < 16; ++rr) accO[cb][rr] = 0.0f;
    float m_run = -1e30f, l_run = 0.0f;

    // staging: 128 threads per split stage K(8KB)+V(8KB) per 32-key tile
    const int ts  = tid & 127;
    const int jr  = ts >> 2;
    const int seg = ts & 3;
    const int j0  = (hf * 4 + s) * 512;
    const char* kg = (const char*)kTt + (size_t)(b * N_) * C_ * 2;
    const char* vg = (const char*)vMat + (size_t)(b * C_ + ts) * N_ * 2;

    i32x4 kst[4], vst[4];
    auto load_tile = [&](int t) {
        const size_t krow = (size_t)(j0 + t * 32 + jr) * 256;
        const size_t vcol = (size_t)(j0 + t * 32) * 2;
        #pragma unroll
        for (int u = 0; u < 4; ++u) {
            kst[u] = *(const i32x4*)(kg + krow + seg * 64 + u * 16);
            vst[u] = *(const i32x4*)(vg + vcol + u * 16);
        }
    };
    // V row layout (64B): quad-swapped so PV A-frags are single b128
    auto write_tile = [&]() {
        #pragma unroll
        for (int u = 0; u < 4; ++u)
            *(i32x4*)(kbuf + jr * 256 + ((seg * 64 + u * 16) ^ ((jr & 7) << 4))) = kst[u];
        const int vsw = ((ts >> 1) & 3) << 4;
        char* vrow = vbuf + ts * 64;
        i32x4 w;
        w[0] = vst[0][0]; w[1] = vst[0][1]; w[2] = vst[1][0]; w[3] = vst[1][1];
        *(i32x4*)(vrow + (0 ^ vsw)) = w;
        w[0] = vst[0][2]; w[1] = vst[0][3]; w[2] = vst[1][2]; w[3] = vst[1][3];
        *(i32x4*)(vrow + (16 ^ vsw)) = w;
        w[0] = vst[2][0]; w[1] = vst[2][1]; w[2] = vst[3][0]; w[3] = vst[3][1];
        *(i32x4*)(vrow + (32 ^ vsw)) = w;
        w[0] = vst[2][2]; w[1] = vst[2][3]; w[2] = vst[3][2]; w[3] = vst[3][3];
        *(i32x4*)(vrow + (48 ^ vsw)) = w;
    };

    load_tile(0);
    write_tile();
    __syncthreads();

    #pragma unroll 1
    for (int t = 0; t < 16; ++t) {
        if (t + 1 < 16) load_tile(t + 1);     // global->regs, hides under compute

        // E^T[j][i] = sum_c K[c,j] Q[c,i]
        f32x16 ea, eb;
        #pragma unroll
        for (int rr = 0; rr < 16; ++rr) { ea[rr] = 0.0f; eb[rr] = 0.0f; }
        {
            const char* krow = kbuf + l31 * 256;
            const int   swz  = (l31 & 7) << 4;
            #pragma unroll
            for (int ch = 0; ch < 8; ch += 2) {
                bf16x8 k0 = __builtin_bit_cast(bf16x8,
                    *(const i32x4*)(krow + ((ch * 32 + 16 * h) ^ swz)));
                ea = __builtin_amdgcn_mfma_f32_32x32x16_bf16(k0, qf[ch], ea, 0, 0, 0);
                bf16x8 k1 = __builtin_bit_cast(bf16x8,
                    *(const i32x4*)(krow + (((ch + 1) * 32 + 16 * h) ^ swz)));
                eb = __builtin_amdgcn_mfma_f32_32x32x16_bf16(k1, qf[ch + 1], eb, 0, 0, 0);
            }
        }
        f32x16 e;
        #pragma unroll
        for (int rr = 0; rr < 16; ++rr) e[rr] = ea[rr] + eb[rr];

        // ---- online softmax (log2 domain; q pre-scaled by log2e) ----
        float a0 = fmaxf(fmaxf(e[0], e[1]), fmaxf(e[2], e[3]));
        float a1 = fmaxf(fmaxf(e[4], e[5]), fmaxf(e[6], e[7]));
        float a2 = fmaxf(fmaxf(e[8], e[9]), fmaxf(e[10], e[11]));
        float a3 = fmaxf(fmaxf(e[12], e[13]), fmaxf(e[14], e[15]));
        float mt = fmaxf(fmaxf(a0, a1), fmaxf(a2, a3));
        mt = fmaxf(mt, __shfl_xor(mt, 32, 64));
        if (!__all(mt <= m_run + 8.0f)) {      // defer-max (T13)
            const float mn = fmaxf(m_run, mt);
            const float sc = exp2f(m_run - mn);
            l_run *= sc;
            #pragma unroll
            for (int cb = 0; cb < 4; ++cb)
                #pragma unroll
                for (int rr = 0; rr < 16; ++rr) accO[cb][rr] *= sc;
            m_run = mn;
        }
        float rs = 0.0f;
        #pragma unroll
        for (int rr = 0; rr < 16; ++rr) {
            float pv = exp2f(e[rr] - m_run); e[rr] = pv; rs += pv;
        }
        rs += __shfl_xor(rs, 32, 64);
        l_run += rs;

        // pack P (k' map M2: k' = 8*(e>>2) + 4h + (e&3))
        i32x4 p0, p1;
        p0[0] = pk2(e[0], e[1]);   p0[1] = pk2(e[2], e[3]);
        p0[2] = pk2(e[4], e[5]);   p0[3] = pk2(e[6], e[7]);
        p1[0] = pk2(e[8], e[9]);   p1[1] = pk2(e[10], e[11]);
        p1[2] = pk2(e[12], e[13]); p1[3] = pk2(e[14], e[15]);
        const bf16x8 pf0 = __builtin_bit_cast(bf16x8, p0);
        const bf16x8 pf1 = __builtin_bit_cast(bf16x8, p1);

        // ---- accO[c][i] += sum_j V[c,j] P[j,i] ----
        const int vsw2 = ((l31 >> 1) & 3) << 4;
        #pragma unroll
        for (int cb = 0; cb < 4; ++cb) {
            const char* vrow = vbuf + (cb * 32 + l31) * 64;
            bf16x8 v0 = __builtin_bit_cast(bf16x8,
                *(const i32x4*)(vrow + ((16 * h) ^ vsw2)));
            accO[cb] = __builtin_amdgcn_mfma_f32_32x32x16_bf16(v0, pf0, accO[cb], 0, 0, 0);
            bf16x8 v1 = __builtin_bit_cast(bf16x8,
                *(const i32x4*)(vrow + ((32 + 16 * h) ^ vsw2)));
            accO[cb] = __builtin_amdgcn_mfma_f32_32x32x16_bf16(v1, pf1, accO[cb], 0, 0, 0);
        }

        if (t + 1 < 16) {
            __syncthreads();                   // readers done with tile t
            write_tile();
            __syncthreads();                   // tile t+1 visible
        }
    }
    __syncthreads();                           // protect smem reuse below

    // ---- combine the 4 in-WG splits; write partial O (bf16) + (M,L) ----
    float* comb = (float*)smem;                // [8][1024]
    float* ml   = (float*)(smem + 32768);      // [8][64]
    if (h == 0) {
        ml[(qb * 4 + s) * 64 + l31]      = m_run;
        ml[(qb * 4 + s) * 64 + 32 + l31] = l_run;
    }
    __syncthreads();
    float wgt[4];
    float Mh, Lh;
    {
        float ms[4], ls[4];
        #pragma unroll
        for (int s2 = 0; s2 < 4; ++s2) {
            ms[s2] = ml[(qb * 4 + s2) * 64 + l31];
            ls[s2] = ml[(qb * 4 + s2) * 64 + 32 + l31];
        }
        Mh = fmaxf(fmaxf(ms[0], ms[1]), fmaxf(ms[2], ms[3]));
        Lh = 0.0f;
        #pragma unroll
        for (int s2 = 0; s2 < 4; ++s2) { wgt[s2] = exp2f(ms[s2] - Mh); Lh += ls[s2] * wgt[s2]; }
    }
    if (s == 0 && h == 0)
        mlG[(size_t)(hf * B_ + b) * N_ + i0 + l31] = make_float2(Mh, Lh);

    #pragma unroll
    for (int cb = 0; cb < 4; ++cb) {
        __syncthreads();
        #pragma unroll
        for (int rr = 0; rr < 16; ++rr)
            comb[(qb * 4 + s) * 1024 + ((rr & 3) + 8 * (rr >> 2) + 4 * h) * 32 + l31] = accO[cb][rr];
        __syncthreads();
        #pragma unroll
        for (int r2 = 0; r2 < 4; ++r2) {
            const int cl = 8 * s + 2 * r2 + h;
            float v = 0.0f;
            #pragma unroll
            for (int s2 = 0; s2 < 4; ++s2)
                v += wgt[s2] * comb[(qb * 4 + s2) * 1024 + cl * 32 + l31];
            const int cg = cb * 32 + cl;
            pO[(size_t)((hf * B_ + b) * C_ + cg) * N_ + i0 + l31] = (unsigned short)bfbits(v);
        }
    }
}

// ---------------- merge two key-halves + residual -----------------------
__global__ __launch_bounds__(256) void merge_kernel(
    const float* __restrict__ x,
    const unsigned short* __restrict__ pO,   // [2][B][C][N] bf16
    const float2* __restrict__ mlG,          // [2][B][N]
    float* __restrict__ out)
{
    const int idx = blockIdx.x * 256 + threadIdx.x;   // over B*C*N/4
    const int nq  = idx & (N_ / 4 - 1);
    const int bc  = idx >> 10;                        // b*C + c
    const int b   = bc >> 7;
    const size_t off = (size_t)bc * N_ + nq * 4;

    i32x2 r0 = *(const i32x2*)(pO + off);
    i32x2 r1 = *(const i32x2*)(pO + (size_t)B_ * C_ * N_ + off);
    float4 xv = *(const float4*)(x + off);
    const float2* ml0 = mlG + (size_t)b * N_ + nq * 4;
    const float2* ml1 = mlG + (size_t)(B_ + b) * N_ + nq * 4;

    float p0[4], p1[4];
    p0[0] = bf2f((unsigned short)(r0[0] & 0xffff));
    p0[1] = bf2f((unsigned short)((unsigned)r0[0] >> 16));
    p0[2] = bf2f((unsigned short)(r0[1] & 0xffff));
    p0[3] = bf2f((unsigned short)((unsigned)r0[1] >> 16));
    p1[0] = bf2f((unsigned short)(r1[0] & 0xffff));
    p1[1] = bf2f((unsigned short)((unsigned)r1[0] >> 16));
    p1[2] = bf2f((unsigned short)(r1[1] & 0xffff));
    p1[3] = bf2f((unsigned short)((unsigned)r1[1] >> 16));

    float r[4];
    #pragma unroll
    for (int j = 0; j < 4; ++j) {
        float2 a = ml0[j], c = ml1[j];
        float M  = fmaxf(a.x, c.x);
        float w0 = exp2f(a.x - M), w1 = exp2f(c.x - M);
        float L  = w0 * a.y + w1 * c.y;
        r[j] = (w0 * p0[j] + w1 * p1[j]) / L;
    }
    float4 ov;
    ov.x = xv.x + r[0]; ov.y = xv.y + r[1];
    ov.z = xv.z + r[2]; ov.w = xv.w + r[3];
    *(float4*)(out + off) = ov;
}

extern "C" void kernel_launch(void* const* d_in, const int* in_sizes, int n_in,
                              void* d_out, int out_size, void* d_ws, size_t ws_size,
                              hipStream_t stream)
{
    const float* x  = (const float*)d_in[0];
    const float* Wq = (const float*)d_in[1];
    const float* bq = (const float*)d_in[2];
    const float* Wk = (const float*)d_in[3];
    const float* bk = (const float*)d_in[4];
    const float* Wv = (const float*)d_in[5];
    const float* bv = (const float*)d_in[6];
    float* out = (float*)d_out;

    unsigned short* qT = (unsigned short*)d_ws;              // [B][N][C] bf16 (log2e-scaled q)
    unsigned short* kT = qT + (size_t)B_ * N_ * C_;          // [B][N][C] bf16
    unsigned short* vM = kT + (size_t)B_ * N_ * C_;          // [B][C][N] bf16
    unsigned short* pO = vM + (size_t)B_ * C_ * N_;          // [2][B][C][N] bf16
    float2* mlG = (float2*)(pO + (size_t)2 * B_ * C_ * N_);  // [2][B][N]

    proj_kernel<<<384, 256, 0, stream>>>(x, Wq, bq, Wk, bk, Wv, bv, qT, kT, vM);
    attn_half_kernel<<<512, 512, 0, stream>>>(qT, kT, vM, pO, mlG);
    merge_kernel<<<(B_ * C_ * N_ / 4) / 256, 256, 0, stream>>>(x, pO, mlG, out);
}

// Round 5
// 84.929 us; speedup vs baseline: 3.2822x; 3.2822x over previous
//
#include <hip/hip_runtime.h>

#define B_ 4
#define C_ 128
#define N_ 4096
#define LOG2E 1.44269504088896340736f
#define KB_PER_B (C_ * N_ * 2)          // 1 MiB per batch for kQ / vQ

typedef __bf16 bf16x8 __attribute__((ext_vector_type(8)));
typedef float  f32x16 __attribute__((ext_vector_type(16)));
typedef int    i32x4  __attribute__((ext_vector_type(4)));
typedef int    i32x2  __attribute__((ext_vector_type(2)));

static __device__ __forceinline__ unsigned int bfbits(float f) {
    unsigned int u = __float_as_uint(f);
    u += 0x7FFFu + ((u >> 16) & 1u);   // round-to-nearest-even
    return u >> 16;
}
static __device__ __forceinline__ int pk2(float lo, float hi) {
    return (int)(bfbits(lo) | (bfbits(hi) << 16));
}
static __device__ __forceinline__ float bf2f(unsigned short u) {
    return __uint_as_float((unsigned int)u << 16);
}

// 16B global -> LDS. DMA writes lds_base + lane*16 (wave-uniform base).
static __device__ __forceinline__ void stage16(const void* g_lane, char* lds_base, int lane16) {
#if __has_builtin(__builtin_amdgcn_global_load_lds)
    __builtin_amdgcn_global_load_lds(
        (const __attribute__((address_space(1))) void*)g_lane,
        (__attribute__((address_space(3))) void*)lds_base, 16, 0, 0);
    (void)lane16;
#else
    *(i32x4*)(lds_base + lane16) = *(const i32x4*)g_lane;
#endif
}

// quad-swap position for V layout: swap bits 2,3 of within-32 key index
static __device__ __forceinline__ int qswap(int col) {
    return (col & ~12) | ((col & 4) << 1) | ((col & 8) >> 1);
}

// ---------------- projection: q/k/v = W @ x + b (1x1 conv) -------------
// qT [B][N][C] bf16 (q scaled by log2e).
// kQ [B][tile][jr 32][chunk16B c'] with c' = chanchunk ^ (jr&15)  (swizzle baked)
// vQ [B][tile][c 128][chunk16B c'] quad-swapped keys, c' = lc ^ (((c>>1)^(c>>3))&3)
__global__ __launch_bounds__(256) void proj_kernel(
    const float* __restrict__ x,
    const float* __restrict__ Wq, const float* __restrict__ bq,
    const float* __restrict__ Wk, const float* __restrict__ bk,
    const float* __restrict__ Wv, const float* __restrict__ bv,
    unsigned short* __restrict__ qT, char* __restrict__ kQ,
    char* __restrict__ vQ)
{
    __shared__ __align__(16) char wlds[32768];   // W bf16, swizzled rows (256B)

    const int tid  = threadIdx.x;
    const int wave = tid >> 6;
    const int lane = tid & 63;
    const int col  = lane & 31;
    const int h    = lane >> 5;

    const int jw  = blockIdx.x * 4 + wave;   // 0..1535 = mat*512 + b*128 + nb
    const int mat = jw >> 9;                 // uniform per WG
    const int rem = jw & 511;
    const int b   = rem >> 7;
    const int nb  = rem & 127;
    const int n   = nb * 32 + col;

    const float* W    = (mat == 0) ? Wq : (mat == 1) ? Wk : Wv;
    const float* bias = (mat == 0) ? bq : (mat == 1) ? bk : bv;
    const float  scale = (mat == 0) ? LOG2E : 1.0f;

    #pragma unroll
    for (int k = 0; k < 16; ++k) {
        const int q = tid + k * 256;          // quad index, 4 floats each
        const int o = q >> 5;                 // W row (output channel)
        const int g = q & 31;                 // 8B granule within row
        float4 w = *((const float4*)W + q);
        i32x2 d;
        d[0] = pk2(w.x * scale, w.y * scale);
        d[1] = pk2(w.z * scale, w.w * scale);
        *(i32x2*)(wlds + o * 256 + ((((g >> 1) ^ (o & 15)) << 4) | ((g & 1) * 8))) = d;
    }
    __syncthreads();

    bf16x8 xf[8];
    const float* xcol = x + (size_t)b * C_ * N_ + n;
    #pragma unroll
    for (int ch = 0; ch < 8; ++ch) {
        const int c0 = ch * 16 + 8 * h;
        i32x4 r;
        r[0] = pk2(xcol[(size_t)(c0 + 0) * N_], xcol[(size_t)(c0 + 1) * N_]);
        r[1] = pk2(xcol[(size_t)(c0 + 2) * N_], xcol[(size_t)(c0 + 3) * N_]);
        r[2] = pk2(xcol[(size_t)(c0 + 4) * N_], xcol[(size_t)(c0 + 5) * N_]);
        r[3] = pk2(xcol[(size_t)(c0 + 6) * N_], xcol[(size_t)(c0 + 7) * N_]);
        xf[ch] = __builtin_bit_cast(bf16x8, r);
    }

    f32x16 acc[4];
    #pragma unroll
    for (int ob = 0; ob < 4; ++ob)
        #pragma unroll
        for (int rr = 0; rr < 16; ++rr) acc[ob][rr] = 0.0f;

    #pragma unroll
    for (int ch = 0; ch < 8; ++ch) {
        #pragma unroll
        for (int ob = 0; ob < 4; ++ob) {
            const char* wrow = wlds + (ob * 32 + col) * 256;
            bf16x8 wf = __builtin_bit_cast(bf16x8,
                *(const i32x4*)(wrow + (((ch * 2 + h) ^ (col & 15)) << 4)));
            acc[ob] = __builtin_amdgcn_mfma_f32_32x32x16_bf16(
                wf, xf[ch], acc[ob], 0, 0, 0);
        }
    }

    if (mat == 0) {
        unsigned short* dst = qT + (size_t)(b * N_ + n) * C_;
        #pragma unroll
        for (int ob = 0; ob < 4; ++ob) {
            #pragma unroll
            for (int qd = 0; qd < 4; ++qd) {
                const int obase = ob * 32 + 8 * qd + 4 * h;
                const float f0 = acc[ob][4 * qd + 0] + bias[obase + 0] * scale;
                const float f1 = acc[ob][4 * qd + 1] + bias[obase + 1] * scale;
                const float f2 = acc[ob][4 * qd + 2] + bias[obase + 2] * scale;
                const float f3 = acc[ob][4 * qd + 3] + bias[obase + 3] * scale;
                i32x2 st; st[0] = pk2(f0, f1); st[1] = pk2(f2, f3);
                *(i32x2*)(dst + obase) = st;
            }
        }
    } else if (mat == 1) {
        char* dst = kQ + (size_t)b * KB_PER_B + (size_t)nb * 8192 + (n & 31) * 256;
        const int jrx = n & 15;
        #pragma unroll
        for (int ob = 0; ob < 4; ++ob) {
            #pragma unroll
            for (int qd = 0; qd < 4; ++qd) {
                const int obase = ob * 32 + 8 * qd + 4 * h;
                const float f0 = acc[ob][4 * qd + 0] + bias[obase + 0];
                const float f1 = acc[ob][4 * qd + 1] + bias[obase + 1];
                const float f2 = acc[ob][4 * qd + 2] + bias[obase + 2];
                const float f3 = acc[ob][4 * qd + 3] + bias[obase + 3];
                i32x2 st; st[0] = pk2(f0, f1); st[1] = pk2(f2, f3);
                *(i32x2*)(dst + ((((ob * 4 + qd) ^ jrx) << 4) | (8 * h))) = st;
            }
        }
    } else {
        char* dst = vQ + (size_t)b * KB_PER_B + (size_t)nb * 8192;
        const int p  = qswap(col);
        const int pb = (p * 2) & 15;          // byte within 16B chunk
        const int lc = p >> 3;                // logical chunk 0..3
        #pragma unroll
        for (int ob = 0; ob < 4; ++ob) {
            #pragma unroll
            for (int rr = 0; rr < 16; ++rr) {
                const int o = ob * 32 + (rr & 3) + 8 * (rr >> 2) + 4 * h;
                const int vs = ((o >> 1) ^ (o >> 3)) & 3;
                *(unsigned short*)(dst + o * 64 + (((lc ^ vs) << 4) | pb)) =
                    (unsigned short)bfbits(acc[ob][rr] + bias[o]);
            }
        }
    }
}

// ---------------- flash attention over N/NS keys per WG ----------------
// 256*NS WGs x 256 thr (3 WGs/CU). 4 waves = 2 qb(32q) x 2 splits.
// global_load_lds staging, single-buffered 32-key tiles.
template<int NS>
__global__ __launch_bounds__(256, 3) void attn_kernel(
    const unsigned short* __restrict__ qT,
    const char* __restrict__ kQ,
    const char* __restrict__ vQ,
    unsigned short* __restrict__ pO,  // [NS][B][C][N] bf16 (un-normalized)
    float2* __restrict__ mlG)         // [NS][B][N] (M, L)
{
    __shared__ __align__(16) char smem[32768];

    const int tid  = threadIdx.x;
    const int w    = tid >> 6;
    const int lane = tid & 63;
    const int l31  = lane & 31;
    const int h    = lane >> 5;
    const int s    = w & 1;            // key split within WG
    const int qb   = w >> 1;           // q block within WG

    // XCD-friendly decode: each XCD-pair owns one batch
    const int orig = blockIdx.x;
    const int b    = (orig & 7) >> 1;
    const int idx  = ((orig >> 3) << 1) | (orig & 1);   // 0..64*NS-1
    const int quarter = idx & (NS - 1);
    const int qg   = idx >> (NS == 4 ? 2 : 1);          // 0..63
    const int i0   = qg * 64 + qb * 32;

    const int NT  = N_ / (NS * 64);                      // tiles per split-wave
    const int tt0 = (quarter * (N_ / NS) + s * (N_ / (2 * NS))) >> 5;

    char* kbuf = smem + s * 16384;
    char* vbuf = kbuf + 8192;
    const char* kq0 = kQ + (size_t)b * KB_PER_B + (size_t)tt0 * 8192;
    const char* vq0 = vQ + (size_t)b * KB_PER_B + (size_t)tt0 * 8192;

    // Q fragments: element e of chunk ch <-> c = ch*16 + 8h + e
    bf16x8 qf[8];
    {
        const unsigned short* qrow = qT + (size_t)(b * N_ + i0 + l31) * C_;
        #pragma unroll
        for (int ch = 0; ch < 8; ++ch)
            qf[ch] = __builtin_bit_cast(bf16x8, *(const i32x4*)(qrow + ch * 16 + 8 * h));
    }

    f32x16 accO[4];
    #pragma unroll
    for (int cb = 0; cb < 4; ++cb)
        #pragma unroll
        for (int rr = 0; rr < 16; ++rr) accO[cb][rr] = 0.0f;
    float m_run = -1e30f, l_run = 0.0f;

    const int lane16 = lane * 16;
    auto stage = [&](int t) {
        const char* ks = kq0 + (size_t)t * 8192 + qb * 4096 + lane16;
        const char* vs = vq0 + (size_t)t * 8192 + qb * 4096 + lane16;
        char* kd = kbuf + qb * 4096;
        char* vd = vbuf + qb * 4096;
        #pragma unroll
        for (int u = 0; u < 4; ++u) {
            stage16(ks + u * 1024, kd + u * 1024, lane16);
            stage16(vs + u * 1024, vd + u * 1024, lane16);
        }
    };

    stage(0);
    __syncthreads();

    #pragma unroll 1
    for (int t = 0; t < NT; ++t) {
        // ---- E^T[j][i] = sum_c K[c,j] Q[c,i] ----
        f32x16 e;
        #pragma unroll
        for (int rr = 0; rr < 16; ++rr) e[rr] = 0.0f;
        {
            const char* krow = kbuf + l31 * 256;
            const int   kx   = l31 & 15;
            #pragma unroll
            for (int ch = 0; ch < 8; ++ch) {
                bf16x8 kf = __builtin_bit_cast(bf16x8,
                    *(const i32x4*)(krow + (((ch * 2 + h) ^ kx) << 4)));
                e = __builtin_amdgcn_mfma_f32_32x32x16_bf16(kf, qf[ch], e, 0, 0, 0);
            }
        }

        // ---- online softmax (log2 domain; q pre-scaled by log2e) ----
        float a0 = fmaxf(fmaxf(e[0], e[1]), fmaxf(e[2], e[3]));
        float a1 = fmaxf(fmaxf(e[4], e[5]), fmaxf(e[6], e[7]));
        float a2 = fmaxf(fmaxf(e[8], e[9]), fmaxf(e[10], e[11]));
        float a3 = fmaxf(fmaxf(e[12], e[13]), fmaxf(e[14], e[15]));
        float mt = fmaxf(fmaxf(a0, a1), fmaxf(a2, a3));
        mt = fmaxf(mt, __shfl_xor(mt, 32, 64));
        if (!__all(mt <= m_run + 8.0f)) {      // defer-max (T13)
            const float mn = fmaxf(m_run, mt);
            const float sc = exp2f(m_run - mn);
            l_run *= sc;
            #pragma unroll
            for (int cb = 0; cb < 4; ++cb)
                #pragma unroll
                for (int rr = 0; rr < 16; ++rr) accO[cb][rr] *= sc;
            m_run = mn;
        }
        float rs = 0.0f;
        #pragma unroll
        for (int rr = 0; rr < 16; ++rr) {
            float pv = exp2f(e[rr] - m_run); e[rr] = pv; rs += pv;
        }
        rs += __shfl_xor(rs, 32, 64);
        l_run += rs;

        // pack P (k' map: k' = 8*(e>>2) + 4h + (e&3))
        i32x4 p0, p1;
        p0[0] = pk2(e[0], e[1]);   p0[1] = pk2(e[2], e[3]);
        p0[2] = pk2(e[4], e[5]);   p0[3] = pk2(e[6], e[7]);
        p1[0] = pk2(e[8], e[9]);   p1[1] = pk2(e[10], e[11]);
        p1[2] = pk2(e[12], e[13]); p1[3] = pk2(e[14], e[15]);
        const bf16x8 pf0 = __builtin_bit_cast(bf16x8, p0);
        const bf16x8 pf1 = __builtin_bit_cast(bf16x8, p1);

        // ---- accO[c][i] += sum_j V[c,j] P[j,i] ----
        const int vsw = ((l31 >> 1) ^ (l31 >> 3)) & 3;
        #pragma unroll
        for (int cb = 0; cb < 4; ++cb) {
            const char* vrow = vbuf + (cb * 32 + l31) * 64;
            bf16x8 v0 = __builtin_bit_cast(bf16x8,
                *(const i32x4*)(vrow + ((h ^ vsw) << 4)));
            accO[cb] = __builtin_amdgcn_mfma_f32_32x32x16_bf16(v0, pf0, accO[cb], 0, 0, 0);
            bf16x8 v1 = __builtin_bit_cast(bf16x8,
                *(const i32x4*)(vrow + (((2 | h) ^ vsw) << 4)));
            accO[cb] = __builtin_amdgcn_mfma_f32_32x32x16_bf16(v1, pf1, accO[cb], 0, 0, 0);
        }

        __syncthreads();                       // all waves done reading tile t
        if (t + 1 < NT) {
            stage(t + 1);
            __syncthreads();                   // drain DMA; tile t+1 visible
        }
    }

    // ---- combine the 2 in-WG splits; write partial O (bf16) + (M,L) ----
    float* comb = (float*)smem;                // [4 w][32 cl][32 i] f32 = 16KB
    float* mlS  = (float*)(smem + 16384);      // [4 w][64]
    if (h == 0) {
        mlS[w * 64 + l31]      = m_run;
        mlS[w * 64 + 32 + l31] = l_run;
    }
    __syncthreads();
    float wgt0, wgt1, Mh, Lh;
    {
        float m0 = mlS[(qb * 2 + 0) * 64 + l31], l0 = mlS[(qb * 2 + 0) * 64 + 32 + l31];
        float m1 = mlS[(qb * 2 + 1) * 64 + l31], l1 = mlS[(qb * 2 + 1) * 64 + 32 + l31];
        Mh = fmaxf(m0, m1);
        wgt0 = exp2f(m0 - Mh); wgt1 = exp2f(m1 - Mh);
        Lh = wgt0 * l0 + wgt1 * l1;
    }
    if (s == 0 && h == 0)
        mlG[((size_t)quarter * B_ + b) * N_ + i0 + l31] = make_float2(Mh, Lh);

    unsigned short* pOq = pO + ((size_t)quarter * B_ + b) * C_ * N_;
    #pragma unroll
    for (int cb = 0; cb < 4; ++cb) {
        __syncthreads();
        #pragma unroll
        for (int rr = 0; rr < 16; ++rr)
            comb[w * 1024 + ((rr & 3) + 8 * (rr >> 2) + 4 * h) * 32 + l31] = accO[cb][rr];
        __syncthreads();
        #pragma unroll
        for (int r2 = 0; r2 < 8; ++r2) {
            const int cl = s * 16 + r2 * 2 + h;
            float v = wgt0 * comb[(qb * 2 + 0) * 1024 + cl * 32 + l31]
                    + wgt1 * comb[(qb * 2 + 1) * 1024 + cl * 32 + l31];
            pOq[(size_t)(cb * 32 + cl) * N_ + i0 + l31] = (unsigned short)bfbits(v);
        }
    }
}

// ---------------- merge NS key-range partials + residual ----------------
template<int NS>
__global__ __launch_bounds__(256) void merge_kernel(
    const float* __restrict__ x,
    const unsigned short* __restrict__ pO,   // [NS][B][C][N] bf16
    const float2* __restrict__ mlG,          // [NS][B][N]
    float* __restrict__ out)
{
    const int idx = blockIdx.x * 256 + threadIdx.x;   // over B*C*N/4
    const int nq  = idx & (N_ / 4 - 1);
    const int bc  = idx >> 10;                        // b*C + c
    const int b   = bc >> 7;
    const size_t off = (size_t)bc * N_ + nq * 4;

    float4 xv = *(const float4*)(x + off);

    float2 ml[NS][4];
    #pragma unroll
    for (int q = 0; q < NS; ++q) {
        const float2* mp = mlG + ((size_t)q * B_ + b) * N_ + nq * 4;
        #pragma unroll
        for (int j = 0; j < 4; ++j) ml[q][j] = mp[j];
    }
    float M[4];
    #pragma unroll
    for (int j = 0; j < 4; ++j) {
        M[j] = ml[0][j].x;
        #pragma unroll
        for (int q = 1; q < NS; ++q) M[j] = fmaxf(M[j], ml[q][j].x);
    }
    float num[4] = {0, 0, 0, 0}, den[4] = {0, 0, 0, 0};
    #pragma unroll
    for (int q = 0; q < NS; ++q) {
        i32x2 r = *(const i32x2*)(pO + (size_t)q * B_ * C_ * N_ + off);
        float p[4];
        p[0] = bf2f((unsigned short)(r[0] & 0xffff));
        p[1] = bf2f((unsigned short)((unsigned)r[0] >> 16));
        p[2] = bf2f((unsigned short)(r[1] & 0xffff));
        p[3] = bf2f((unsigned short)((unsigned)r[1] >> 16));
        #pragma unroll
        for (int j = 0; j < 4; ++j) {
            float wq = exp2f(ml[q][j].x - M[j]);
            num[j] += wq * p[j];
            den[j] += wq * ml[q][j].y;
        }
    }
    float4 ov;
    ov.x = xv.x + num[0] / den[0];
    ov.y = xv.y + num[1] / den[1];
    ov.z = xv.z + num[2] / den[2];
    ov.w = xv.w + num[3] / den[3];
    *(float4*)(out + off) = ov;
}

extern "C" void kernel_launch(void* const* d_in, const int* in_sizes, int n_in,
                              void* d_out, int out_size, void* d_ws, size_t ws_size,
                              hipStream_t stream)
{
    const float* x  = (const float*)d_in[0];
    const float* Wq = (const float*)d_in[1];
    const float* bq = (const float*)d_in[2];
    const float* Wk = (const float*)d_in[3];
    const float* bk = (const float*)d_in[4];
    const float* Wv = (const float*)d_in[5];
    const float* bv = (const float*)d_in[6];
    float* out = (float*)d_out;

    unsigned short* qT = (unsigned short*)d_ws;              // 4 MiB
    char* kQ = (char*)(qT + (size_t)B_ * N_ * C_);           // 4 MiB
    char* vQ = kQ + (size_t)B_ * KB_PER_B;                   // 4 MiB
    unsigned short* pO = (unsigned short*)(vQ + (size_t)B_ * KB_PER_B);

    const size_t slotO  = (size_t)B_ * C_ * N_;              // bf16 elems / slot
    const size_t slotML = (size_t)B_ * N_;                   // float2 / slot
    const size_t need4  = 3ull * B_ * N_ * C_ * 2 + 4 * (slotO * 2 + slotML * 8);

    proj_kernel<<<384, 256, 0, stream>>>(x, Wq, bq, Wk, bk, Wv, bv, qT, kQ, vQ);

    if (ws_size >= need4) {
        float2* mlG = (float2*)(pO + 4 * slotO);
        attn_kernel<4><<<1024, 256, 0, stream>>>(qT, kQ, vQ, pO, mlG);
        merge_kernel<4><<<(B_ * C_ * N_ / 4) / 256, 256, 0, stream>>>(x, pO, mlG, out);
    } else {
        float2* mlG = (float2*)(pO + 2 * slotO);
        attn_kernel<2><<<512, 256, 0, stream>>>(qT, kQ, vQ, pO, mlG);
        merge_kernel<2><<<(B_ * C_ * N_ / 4) / 256, 256, 0, stream>>>(x, pO, mlG, out);
    }
}

// Round 6
// 84.857 us; speedup vs baseline: 3.2850x; 1.0008x over previous
//
#include <hip/hip_runtime.h>

#define B_ 4
#define C_ 128
#define N_ 4096
#define LOG2E 1.44269504088896340736f
#define KB_PER_B (C_ * N_ * 2)          // 1 MiB per batch for kQ / vQ

typedef __bf16 bf16x8 __attribute__((ext_vector_type(8)));
typedef float  f32x16 __attribute__((ext_vector_type(16)));
typedef int    i32x4  __attribute__((ext_vector_type(4)));
typedef int    i32x2  __attribute__((ext_vector_type(2)));

static __device__ __forceinline__ unsigned int bfbits(float f) {
    unsigned int u = __float_as_uint(f);
    u += 0x7FFFu + ((u >> 16) & 1u);   // round-to-nearest-even
    return u >> 16;
}
static __device__ __forceinline__ int pk2(float lo, float hi) {
    return (int)(bfbits(lo) | (bfbits(hi) << 16));
}
static __device__ __forceinline__ float bf2f(unsigned short u) {
    return __uint_as_float((unsigned int)u << 16);
}

// 16B global -> LDS. DMA writes lds_base + lane*16 (wave-uniform base).
static __device__ __forceinline__ void stage16(const void* g_lane, char* lds_base, int lane16) {
#if __has_builtin(__builtin_amdgcn_global_load_lds)
    __builtin_amdgcn_global_load_lds(
        (const __attribute__((address_space(1))) void*)g_lane,
        (__attribute__((address_space(3))) void*)lds_base, 16, 0, 0);
    (void)lane16;
#else
    *(i32x4*)(lds_base + lane16) = *(const i32x4*)g_lane;
#endif
}

// quad-swap position for V layout: swap bits 2,3 of within-32 key index
static __device__ __forceinline__ int qswap(int col) {
    return (col & ~12) | ((col & 4) << 1) | ((col & 8) >> 1);
}

// ---------------- projection: q/k/v = W @ x + b (1x1 conv) -------------
// qT [B][N][C] bf16 (q scaled by log2e).
// kQ [B][tile][jr 32][chunk16B c'] with c' = chanchunk ^ (jr&15)  (swizzle baked)
// vQ [B][tile][c 128][chunk16B c'] quad-swapped keys, c' = lc ^ (((c>>1)^(c>>3))&3)
__global__ __launch_bounds__(256) void proj_kernel(
    const float* __restrict__ x,
    const float* __restrict__ Wq, const float* __restrict__ bq,
    const float* __restrict__ Wk, const float* __restrict__ bk,
    const float* __restrict__ Wv, const float* __restrict__ bv,
    unsigned short* __restrict__ qT, char* __restrict__ kQ,
    char* __restrict__ vQ)
{
    __shared__ __align__(16) char wlds[32768];   // W bf16, swizzled rows (256B)

    const int tid  = threadIdx.x;
    const int wave = tid >> 6;
    const int lane = tid & 63;
    const int col  = lane & 31;
    const int h    = lane >> 5;

    const int jw  = blockIdx.x * 4 + wave;   // 0..1535 = mat*512 + b*128 + nb
    const int mat = jw >> 9;                 // uniform per WG
    const int rem = jw & 511;
    const int b   = rem >> 7;
    const int nb  = rem & 127;
    const int n   = nb * 32 + col;

    const float* W    = (mat == 0) ? Wq : (mat == 1) ? Wk : Wv;
    const float* bias = (mat == 0) ? bq : (mat == 1) ? bk : bv;
    const float  scale = (mat == 0) ? LOG2E : 1.0f;

    #pragma unroll
    for (int k = 0; k < 16; ++k) {
        const int q = tid + k * 256;          // quad index, 4 floats each
        const int o = q >> 5;                 // W row (output channel)
        const int g = q & 31;                 // 8B granule within row
        float4 w = *((const float4*)W + q);
        i32x2 d;
        d[0] = pk2(w.x * scale, w.y * scale);
        d[1] = pk2(w.z * scale, w.w * scale);
        *(i32x2*)(wlds + o * 256 + ((((g >> 1) ^ (o & 15)) << 4) | ((g & 1) * 8))) = d;
    }
    __syncthreads();

    bf16x8 xf[8];
    const float* xcol = x + (size_t)b * C_ * N_ + n;
    #pragma unroll
    for (int ch = 0; ch < 8; ++ch) {
        const int c0 = ch * 16 + 8 * h;
        i32x4 r;
        r[0] = pk2(xcol[(size_t)(c0 + 0) * N_], xcol[(size_t)(c0 + 1) * N_]);
        r[1] = pk2(xcol[(size_t)(c0 + 2) * N_], xcol[(size_t)(c0 + 3) * N_]);
        r[2] = pk2(xcol[(size_t)(c0 + 4) * N_], xcol[(size_t)(c0 + 5) * N_]);
        r[3] = pk2(xcol[(size_t)(c0 + 6) * N_], xcol[(size_t)(c0 + 7) * N_]);
        xf[ch] = __builtin_bit_cast(bf16x8, r);
    }

    f32x16 acc[4];
    #pragma unroll
    for (int ob = 0; ob < 4; ++ob)
        #pragma unroll
        for (int rr = 0; rr < 16; ++rr) acc[ob][rr] = 0.0f;

    #pragma unroll
    for (int ch = 0; ch < 8; ++ch) {
        #pragma unroll
        for (int ob = 0; ob < 4; ++ob) {
            const char* wrow = wlds + (ob * 32 + col) * 256;
            bf16x8 wf = __builtin_bit_cast(bf16x8,
                *(const i32x4*)(wrow + (((ch * 2 + h) ^ (col & 15)) << 4)));
            acc[ob] = __builtin_amdgcn_mfma_f32_32x32x16_bf16(
                wf, xf[ch], acc[ob], 0, 0, 0);
        }
    }

    if (mat == 0) {
        unsigned short* dst = qT + (size_t)(b * N_ + n) * C_;
        #pragma unroll
        for (int ob = 0; ob < 4; ++ob) {
            #pragma unroll
            for (int qd = 0; qd < 4; ++qd) {
                const int obase = ob * 32 + 8 * qd + 4 * h;
                const float f0 = acc[ob][4 * qd + 0] + bias[obase + 0] * scale;
                const float f1 = acc[ob][4 * qd + 1] + bias[obase + 1] * scale;
                const float f2 = acc[ob][4 * qd + 2] + bias[obase + 2] * scale;
                const float f3 = acc[ob][4 * qd + 3] + bias[obase + 3] * scale;
                i32x2 st; st[0] = pk2(f0, f1); st[1] = pk2(f2, f3);
                *(i32x2*)(dst + obase) = st;
            }
        }
    } else if (mat == 1) {
        char* dst = kQ + (size_t)b * KB_PER_B + (size_t)nb * 8192 + (n & 31) * 256;
        const int jrx = n & 15;
        #pragma unroll
        for (int ob = 0; ob < 4; ++ob) {
            #pragma unroll
            for (int qd = 0; qd < 4; ++qd) {
                const int obase = ob * 32 + 8 * qd + 4 * h;
                const float f0 = acc[ob][4 * qd + 0] + bias[obase + 0];
                const float f1 = acc[ob][4 * qd + 1] + bias[obase + 1];
                const float f2 = acc[ob][4 * qd + 2] + bias[obase + 2];
                const float f3 = acc[ob][4 * qd + 3] + bias[obase + 3];
                i32x2 st; st[0] = pk2(f0, f1); st[1] = pk2(f2, f3);
                *(i32x2*)(dst + ((((ob * 4 + qd) ^ jrx) << 4) | (8 * h))) = st;
            }
        }
    } else {
        char* dst = vQ + (size_t)b * KB_PER_B + (size_t)nb * 8192;
        const int p  = qswap(col);
        const int pb = (p * 2) & 15;          // byte within 16B chunk
        const int lc = p >> 3;                // logical chunk 0..3
        #pragma unroll
        for (int ob = 0; ob < 4; ++ob) {
            #pragma unroll
            for (int rr = 0; rr < 16; ++rr) {
                const int o = ob * 32 + (rr & 3) + 8 * (rr >> 2) + 4 * h;
                const int vs = ((o >> 1) ^ (o >> 3)) & 3;
                *(unsigned short*)(dst + o * 64 + (((lc ^ vs) << 4) | pb)) =
                    (unsigned short)bfbits(acc[ob][rr] + bias[o]);
            }
        }
    }
}

// ---------------- flash attention over N/NS keys per WG ----------------
// 256*NS WGs x 256 thr (3 WGs/CU). 4 waves = 2 qb(32q) x 2 splits.
// global_load_lds staging, single-buffered 32-key tiles.
template<int NS>
__global__ __launch_bounds__(256, 3) void attn_kernel(
    const unsigned short* __restrict__ qT,
    const char* __restrict__ kQ,
    const char* __restrict__ vQ,
    unsigned short* __restrict__ pO,  // [NS][B][C][N] bf16 (un-normalized)
    float2* __restrict__ mlG)         // [NS][B][N] (M, L)
{
    __shared__ __align__(16) char smem[32768];

    const int tid  = threadIdx.x;
    const int w    = tid >> 6;
    const int lane = tid & 63;
    const int l31  = lane & 31;
    const int h    = lane >> 5;
    const int s    = w & 1;            // key split within WG
    const int qb   = w >> 1;           // q block within WG

    // XCD-friendly decode: each XCD-pair owns one batch
    const int orig = blockIdx.x;
    const int b    = (orig & 7) >> 1;
    const int idx  = ((orig >> 3) << 1) | (orig & 1);   // 0..64*NS-1
    const int quarter = idx & (NS - 1);
    const int qg   = idx >> (NS == 4 ? 2 : 1);          // 0..63
    const int i0   = qg * 64 + qb * 32;

    const int NT  = N_ / (NS * 64);                      // tiles per split-wave
    const int tt0 = (quarter * (N_ / NS) + s * (N_ / (2 * NS))) >> 5;

    char* kbuf = smem + s * 16384;
    char* vbuf = kbuf + 8192;
    const char* kq0 = kQ + (size_t)b * KB_PER_B + (size_t)tt0 * 8192;
    const char* vq0 = vQ + (size_t)b * KB_PER_B + (size_t)tt0 * 8192;

    // Q fragments: element e of chunk ch <-> c = ch*16 + 8h + e
    bf16x8 qf[8];
    {
        const unsigned short* qrow = qT + (size_t)(b * N_ + i0 + l31) * C_;
        #pragma unroll
        for (int ch = 0; ch < 8; ++ch)
            qf[ch] = __builtin_bit_cast(bf16x8, *(const i32x4*)(qrow + ch * 16 + 8 * h));
    }

    f32x16 accO[4];
    #pragma unroll
    for (int cb = 0; cb < 4; ++cb)
        #pragma unroll
        for (int rr = 0; rr < 16; ++rr) accO[cb][rr] = 0.0f;
    float m_run = -1e30f, l_run = 0.0f;

    const int lane16 = lane * 16;
    auto stage = [&](int t) {
        const char* ks = kq0 + (size_t)t * 8192 + qb * 4096 + lane16;
        const char* vs = vq0 + (size_t)t * 8192 + qb * 4096 + lane16;
        char* kd = kbuf + qb * 4096;
        char* vd = vbuf + qb * 4096;
        #pragma unroll
        for (int u = 0; u < 4; ++u) {
            stage16(ks + u * 1024, kd + u * 1024, lane16);
            stage16(vs + u * 1024, vd + u * 1024, lane16);
        }
    };

    stage(0);
    __syncthreads();

    #pragma unroll 1
    for (int t = 0; t < NT; ++t) {
        // ---- E^T[j][i] = sum_c K[c,j] Q[c,i] ----
        f32x16 e;
        #pragma unroll
        for (int rr = 0; rr < 16; ++rr) e[rr] = 0.0f;
        {
            const char* krow = kbuf + l31 * 256;
            const int   kx   = l31 & 15;
            #pragma unroll
            for (int ch = 0; ch < 8; ++ch) {
                bf16x8 kf = __builtin_bit_cast(bf16x8,
                    *(const i32x4*)(krow + (((ch * 2 + h) ^ kx) << 4)));
                e = __builtin_amdgcn_mfma_f32_32x32x16_bf16(kf, qf[ch], e, 0, 0, 0);
            }
        }

        // ---- online softmax (log2 domain; q pre-scaled by log2e) ----
        float a0 = fmaxf(fmaxf(e[0], e[1]), fmaxf(e[2], e[3]));
        float a1 = fmaxf(fmaxf(e[4], e[5]), fmaxf(e[6], e[7]));
        float a2 = fmaxf(fmaxf(e[8], e[9]), fmaxf(e[10], e[11]));
        float a3 = fmaxf(fmaxf(e[12], e[13]), fmaxf(e[14], e[15]));
        float mt = fmaxf(fmaxf(a0, a1), fmaxf(a2, a3));
        mt = fmaxf(mt, __shfl_xor(mt, 32, 64));
        if (!__all(mt <= m_run + 8.0f)) {      // defer-max (T13)
            const float mn = fmaxf(m_run, mt);
            const float sc = exp2f(m_run - mn);
            l_run *= sc;
            #pragma unroll
            for (int cb = 0; cb < 4; ++cb)
                #pragma unroll
                for (int rr = 0; rr < 16; ++rr) accO[cb][rr] *= sc;
            m_run = mn;
        }
        float rs = 0.0f;
        #pragma unroll
        for (int rr = 0; rr < 16; ++rr) {
            float pv = exp2f(e[rr] - m_run); e[rr] = pv; rs += pv;
        }
        rs += __shfl_xor(rs, 32, 64);
        l_run += rs;

        // pack P (k' map: k' = 8*(e>>2) + 4h + (e&3))
        i32x4 p0, p1;
        p0[0] = pk2(e[0], e[1]);   p0[1] = pk2(e[2], e[3]);
        p0[2] = pk2(e[4], e[5]);   p0[3] = pk2(e[6], e[7]);
        p1[0] = pk2(e[8], e[9]);   p1[1] = pk2(e[10], e[11]);
        p1[2] = pk2(e[12], e[13]); p1[3] = pk2(e[14], e[15]);
        const bf16x8 pf0 = __builtin_bit_cast(bf16x8, p0);
        const bf16x8 pf1 = __builtin_bit_cast(bf16x8, p1);

        // ---- accO[c][i] += sum_j V[c,j] P[j,i] ----
        const int vsw = ((l31 >> 1) ^ (l31 >> 3)) & 3;
        #pragma unroll
        for (int cb = 0; cb < 4; ++cb) {
            const char* vrow = vbuf + (cb * 32 + l31) * 64;
            bf16x8 v0 = __builtin_bit_cast(bf16x8,
                *(const i32x4*)(vrow + ((h ^ vsw) << 4)));
            accO[cb] = __builtin_amdgcn_mfma_f32_32x32x16_bf16(v0, pf0, accO[cb], 0, 0, 0);
            bf16x8 v1 = __builtin_bit_cast(bf16x8,
                *(const i32x4*)(vrow + (((2 | h) ^ vsw) << 4)));
            accO[cb] = __builtin_amdgcn_mfma_f32_32x32x16_bf16(v1, pf1, accO[cb], 0, 0, 0);
        }

        __syncthreads();                       // all waves done reading tile t
        if (t + 1 < NT) {
            stage(t + 1);
            __syncthreads();                   // drain DMA; tile t+1 visible
        }
    }

    // ---- combine the 2 in-WG splits; write partial O (bf16) + (M,L) ----
    float* comb = (float*)smem;                // [4 w][32 cl][32 i] f32 = 16KB
    float* mlS  = (float*)(smem + 16384);      // [4 w][64]
    if (h == 0) {
        mlS[w * 64 + l31]      = m_run;
        mlS[w * 64 + 32 + l31] = l_run;
    }
    __syncthreads();
    float wgt0, wgt1, Mh, Lh;
    {
        float m0 = mlS[(qb * 2 + 0) * 64 + l31], l0 = mlS[(qb * 2 + 0) * 64 + 32 + l31];
        float m1 = mlS[(qb * 2 + 1) * 64 + l31], l1 = mlS[(qb * 2 + 1) * 64 + 32 + l31];
        Mh = fmaxf(m0, m1);
        wgt0 = exp2f(m0 - Mh); wgt1 = exp2f(m1 - Mh);
        Lh = wgt0 * l0 + wgt1 * l1;
    }
    if (s == 0 && h == 0)
        mlG[((size_t)quarter * B_ + b) * N_ + i0 + l31] = make_float2(Mh, Lh);

    unsigned short* pOq = pO + ((size_t)quarter * B_ + b) * C_ * N_;
    #pragma unroll
    for (int cb = 0; cb < 4; ++cb) {
        __syncthreads();
        #pragma unroll
        for (int rr = 0; rr < 16; ++rr)
            comb[w * 1024 + ((rr & 3) + 8 * (rr >> 2) + 4 * h) * 32 + l31] = accO[cb][rr];
        __syncthreads();
        #pragma unroll
        for (int r2 = 0; r2 < 8; ++r2) {
            const int cl = s * 16 + r2 * 2 + h;
            float v = wgt0 * comb[(qb * 2 + 0) * 1024 + cl * 32 + l31]
                    + wgt1 * comb[(qb * 2 + 1) * 1024 + cl * 32 + l31];
            pOq[(size_t)(cb * 32 + cl) * N_ + i0 + l31] = (unsigned short)bfbits(v);
        }
    }
}

// ---------------- merge NS key-range partials + residual ----------------
template<int NS>
__global__ __launch_bounds__(256) void merge_kernel(
    const float* __restrict__ x,
    const unsigned short* __restrict__ pO,   // [NS][B][C][N] bf16
    const float2* __restrict__ mlG,          // [NS][B][N]
    float* __restrict__ out)
{
    const int idx = blockIdx.x * 256 + threadIdx.x;   // over B*C*N/4
    const int nq  = idx & (N_ / 4 - 1);
    const int bc  = idx >> 10;                        // b*C + c
    const int b   = bc >> 7;
    const size_t off = (size_t)bc * N_ + nq * 4;

    float4 xv = *(const float4*)(x + off);

    float2 ml[NS][4];
    #pragma unroll
    for (int q = 0; q < NS; ++q) {
        const float2* mp = mlG + ((size_t)q * B_ + b) * N_ + nq * 4;
        #pragma unroll
        for (int j = 0; j < 4; ++j) ml[q][j] = mp[j];
    }
    float M[4];
    #pragma unroll
    for (int j = 0; j < 4; ++j) {
        M[j] = ml[0][j].x;
        #pragma unroll
        for (int q = 1; q < NS; ++q) M[j] = fmaxf(M[j], ml[q][j].x);
    }
    float num[4] = {0, 0, 0, 0}, den[4] = {0, 0, 0, 0};
    #pragma unroll
    for (int q = 0; q < NS; ++q) {
        i32x2 r = *(const i32x2*)(pO + (size_t)q * B_ * C_ * N_ + off);
        float p[4];
        p[0] = bf2f((unsigned short)(r[0] & 0xffff));
        p[1] = bf2f((unsigned short)((unsigned)r[0] >> 16));
        p[2] = bf2f((unsigned short)(r[1] & 0xffff));
        p[3] = bf2f((unsigned short)((unsigned)r[1] >> 16));
        #pragma unroll
        for (int j = 0; j < 4; ++j) {
            float wq = exp2f(ml[q][j].x - M[j]);
            num[j] += wq * p[j];
            den[j] += wq * ml[q][j].y;
        }
    }
    float4 ov;
    ov.x = xv.x + num[0] / den[0];
    ov.y = xv.y + num[1] / den[1];
    ov.z = xv.z + num[2] / den[2];
    ov.w = xv.w + num[3] / den[3];
    *(float4*)(out + off) = ov;
}

extern "C" void kernel_launch(void* const* d_in, const int* in_sizes, int n_in,
                              void* d_out, int out_size, void* d_ws, size_t ws_size,
                              hipStream_t stream)
{
    const float* x  = (const float*)d_in[0];
    const float* Wq = (const float*)d_in[1];
    const float* bq = (const float*)d_in[2];
    const float* Wk = (const float*)d_in[3];
    const float* bk = (const float*)d_in[4];
    const float* Wv = (const float*)d_in[5];
    const float* bv = (const float*)d_in[6];
    float* out = (float*)d_out;

    unsigned short* qT = (unsigned short*)d_ws;              // 4 MiB
    char* kQ = (char*)(qT + (size_t)B_ * N_ * C_);           // 4 MiB
    char* vQ = kQ + (size_t)B_ * KB_PER_B;                   // 4 MiB
    unsigned short* pO = (unsigned short*)(vQ + (size_t)B_ * KB_PER_B);

    const size_t slotO  = (size_t)B_ * C_ * N_;              // bf16 elems / slot
    const size_t slotML = (size_t)B_ * N_;                   // float2 / slot
    const size_t need4  = 3ull * B_ * N_ * C_ * 2 + 4 * (slotO * 2 + slotML * 8);

    proj_kernel<<<384, 256, 0, stream>>>(x, Wq, bq, Wk, bk, Wv, bv, qT, kQ, vQ);

    if (ws_size >= need4) {
        float2* mlG = (float2*)(pO + 4 * slotO);
        attn_kernel<4><<<1024, 256, 0, stream>>>(qT, kQ, vQ, pO, mlG);
        merge_kernel<4><<<(B_ * C_ * N_ / 4) / 256, 256, 0, stream>>>(x, pO, mlG, out);
    } else {
        float2* mlG = (float2*)(pO + 2 * slotO);
        attn_kernel<2><<<512, 256, 0, stream>>>(qT, kQ, vQ, pO, mlG);
        merge_kernel<2><<<(B_ * C_ * N_ / 4) / 256, 256, 0, stream>>>(x, pO, mlG, out);
    }
}

// Round 7
// 72.314 us; speedup vs baseline: 3.8548x; 1.1735x over previous
//
#include <hip/hip_runtime.h>

#define B_ 4
#define C_ 128
#define N_ 4096
#define LOG2E 1.44269504088896340736f
#define KB_PER_B (C_ * N_ * 2)          // 1 MiB per batch for kQ / vQ

typedef __bf16 bf16x8 __attribute__((ext_vector_type(8)));
typedef __bf16 bf16x4 __attribute__((ext_vector_type(4)));
typedef float  f32x16 __attribute__((ext_vector_type(16)));
typedef int    i32x4  __attribute__((ext_vector_type(4)));
typedef int    i32x2  __attribute__((ext_vector_type(2)));

// 16B global -> LDS DMA. LDS dest = wave-uniform base + lane*16.
static __device__ __forceinline__ void stage16(const void* g_lane, char* lds_base, int lane16) {
#if __has_builtin(__builtin_amdgcn_global_load_lds)
    __builtin_amdgcn_global_load_lds(
        (const __attribute__((address_space(1))) void*)g_lane,
        (__attribute__((address_space(3))) void*)lds_base, 16, 0, 0);
    (void)lane16;
#else
    *(i32x4*)(lds_base + lane16) = *(const i32x4*)g_lane;
#endif
}

// ---------------- projection: q/k/v = W @ x + b (1x1 conv) -------------
// qT [B][N][C] bf16 (q scaled by log2e).
// kQ [B][tile64][j 64][chunk16B ^ (j&15)]          (16 KB / 64-key tile)
// vQ [B][tile64][R=c>>1 64][chunk16B ^ (R&15)]     (16 KB / 64-key tile)
//    chunkIdx = (c&1)*8 + 2m + hk; within-chunk M2 key order.
__global__ __launch_bounds__(256) void proj_kernel(
    const float* __restrict__ x,
    const float* __restrict__ Wq, const float* __restrict__ bq,
    const float* __restrict__ Wk, const float* __restrict__ bk,
    const float* __restrict__ Wv, const float* __restrict__ bv,
    unsigned short* __restrict__ qT, char* __restrict__ kQ,
    char* __restrict__ vQ)
{
    __shared__ __align__(16) char wlds[32768];   // W bf16, swizzled rows (256B)

    const int tid  = threadIdx.x;
    const int wave = tid >> 6;
    const int lane = tid & 63;
    const int col  = lane & 31;
    const int h    = lane >> 5;

    const int jw  = blockIdx.x * 4 + wave;   // 0..1535 = mat*512 + b*128 + nb
    const int mat = jw >> 9;                 // uniform per WG
    const int rem = jw & 511;
    const int b   = rem >> 7;
    const int nb  = rem & 127;
    const int n   = nb * 32 + col;

    const float* W    = (mat == 0) ? Wq : (mat == 1) ? Wk : Wv;
    const float* bias = (mat == 0) ? bq : (mat == 1) ? bk : bv;
    const float  scale = (mat == 0) ? LOG2E : 1.0f;

    #pragma unroll
    for (int k = 0; k < 16; ++k) {
        const int q = tid + k * 256;          // quad index, 4 floats each
        const int o = q >> 5;                 // W row (output channel)
        const int g = q & 31;                 // 8B granule within row
        float4 w = *((const float4*)W + q);
        bf16x4 d;
        d[0] = (__bf16)(w.x * scale); d[1] = (__bf16)(w.y * scale);
        d[2] = (__bf16)(w.z * scale); d[3] = (__bf16)(w.w * scale);
        *(bf16x4*)(wlds + o * 256 + ((((g >> 1) ^ (o & 15)) << 4) | ((g & 1) * 8))) = d;
    }
    __syncthreads();

    bf16x8 xf[8];
    const float* xcol = x + (size_t)b * C_ * N_ + n;
    #pragma unroll
    for (int ch = 0; ch < 8; ++ch) {
        const int c0 = ch * 16 + 8 * h;
        bf16x8 v;
        #pragma unroll
        for (int e = 0; e < 8; ++e) v[e] = (__bf16)xcol[(size_t)(c0 + e) * N_];
        xf[ch] = v;
    }

    f32x16 acc[4];
    #pragma unroll
    for (int ob = 0; ob < 4; ++ob)
        #pragma unroll
        for (int rr = 0; rr < 16; ++rr) acc[ob][rr] = 0.0f;

    #pragma unroll
    for (int ch = 0; ch < 8; ++ch) {
        #pragma unroll
        for (int ob = 0; ob < 4; ++ob) {
            const char* wrow = wlds + (ob * 32 + col) * 256;
            bf16x8 wf = __builtin_bit_cast(bf16x8,
                *(const i32x4*)(wrow + (((ch * 2 + h) ^ (col & 15)) << 4)));
            acc[ob] = __builtin_amdgcn_mfma_f32_32x32x16_bf16(
                wf, xf[ch], acc[ob], 0, 0, 0);
        }
    }

    if (mat == 0) {
        unsigned short* dst = qT + (size_t)(b * N_ + n) * C_;
        #pragma unroll
        for (int ob = 0; ob < 4; ++ob) {
            #pragma unroll
            for (int qd = 0; qd < 4; ++qd) {
                const int obase = ob * 32 + 8 * qd + 4 * h;
                bf16x4 d;
                d[0] = (__bf16)(acc[ob][4 * qd + 0] + bias[obase + 0] * scale);
                d[1] = (__bf16)(acc[ob][4 * qd + 1] + bias[obase + 1] * scale);
                d[2] = (__bf16)(acc[ob][4 * qd + 2] + bias[obase + 2] * scale);
                d[3] = (__bf16)(acc[ob][4 * qd + 3] + bias[obase + 3] * scale);
                *(bf16x4*)(dst + obase) = d;
            }
        }
    } else if (mat == 1) {
        const int kt = (nb & 1) * 32 + col;               // key within 64-tile
        char* dst = kQ + (size_t)b * KB_PER_B + (size_t)(nb >> 1) * 16384 + kt * 256;
        const int kx = kt & 15;
        #pragma unroll
        for (int ob = 0; ob < 4; ++ob) {
            #pragma unroll
            for (int qd = 0; qd < 4; ++qd) {
                const int obase = ob * 32 + 8 * qd + 4 * h;
                bf16x4 d;
                d[0] = (__bf16)(acc[ob][4 * qd + 0] + bias[obase + 0]);
                d[1] = (__bf16)(acc[ob][4 * qd + 1] + bias[obase + 1]);
                d[2] = (__bf16)(acc[ob][4 * qd + 2] + bias[obase + 2]);
                d[3] = (__bf16)(acc[ob][4 * qd + 3] + bias[obase + 3]);
                *(bf16x4*)(dst + ((((ob * 4 + qd) ^ kx) << 4) | (8 * h))) = d;
            }
        }
    } else {
        char* dst = vQ + (size_t)b * KB_PER_B + (size_t)(nb >> 1) * 16384;
        const int kt  = (nb & 1) * 32 + col;
        const int m   = kt >> 4;
        const int w16 = kt & 15;
        const int hk  = (w16 >> 2) & 1;
        const int pos = (w16 & 3) | (((w16 >> 3) & 1) << 2);   // M2 element index
        #pragma unroll
        for (int ob = 0; ob < 4; ++ob) {
            #pragma unroll
            for (int rr = 0; rr < 16; ++rr) {
                const int o = ob * 32 + (rr & 3) + 8 * (rr >> 2) + 4 * h;
                const int R = o >> 1;
                const int cidx = (o & 1) * 8 + 2 * m + hk;
                *(unsigned short*)(dst + R * 256 + (((cidx ^ (R & 15)) << 4)) + pos * 2) =
                    __builtin_bit_cast(unsigned short,
                                       (__bf16)(acc[ob][rr] + bias[o]));
            }
        }
    }
}

// ---------------- flash attention over N/NS keys per WG ----------------
// grid = B * (N/128) * NS WGs x 256 thr. 4 waves = 4 q-blocks (128 q) all
// sharing one 64-key tile stream. Double-buffered LDS, 1 barrier/tile.
template<int NS>
__global__ __launch_bounds__(256, 2) void attn_kernel(
    const unsigned short* __restrict__ qT,
    const char* __restrict__ kQ,
    const char* __restrict__ vQ,
    unsigned short* __restrict__ pO,  // [NS][B][C][N] bf16 (un-normalized)
    float2* __restrict__ mlG)         // [NS][B][N] (M, L)
{
    __shared__ __align__(16) char smem[65536];   // 2 x (K 16KB | V 16KB)

    const int tid  = threadIdx.x;
    const int w    = tid >> 6;
    const int lane = tid & 63;
    const int l31  = lane & 31;
    const int h    = lane >> 5;

    const int orig = blockIdx.x;
    const int b    = (orig & 7) >> 1;                  // XCD-pair per batch
    const int idx  = ((orig >> 3) << 1) | (orig & 1);
    const int quarter = idx % NS;
    const int qg   = idx / NS;                         // 0..31
    const int i0   = qg * 128 + w * 32;

    const int NT = N_ / (NS * 64);                     // 64-key tiles per WG
    const char* kq0 = kQ + (size_t)b * KB_PER_B + (size_t)(quarter * NT) * 16384;
    const char* vq0 = vQ + (size_t)b * KB_PER_B + (size_t)(quarter * NT) * 16384;

    // Q fragments: element e of chunk ch <-> c = ch*16 + 8h + e
    bf16x8 qf[8];
    {
        const unsigned short* qrow = qT + (size_t)(b * N_ + i0 + l31) * C_;
        #pragma unroll
        for (int ch = 0; ch < 8; ++ch)
            qf[ch] = __builtin_bit_cast(bf16x8, *(const i32x4*)(qrow + ch * 16 + 8 * h));
    }
    bf16x8 ones;
    #pragma unroll
    for (int e = 0; e < 8; ++e) ones[e] = (__bf16)1.0f;

    f32x16 accO[4];
    #pragma unroll
    for (int cb = 0; cb < 4; ++cb)
        #pragma unroll
        for (int rr = 0; rr < 16; ++rr) accO[cb][rr] = 0.0f;
    f32x16 ls;                                        // P row-sum accumulator
    #pragma unroll
    for (int rr = 0; rr < 16; ++rr) ls[rr] = 0.0f;
    float m_run = -1e30f;

    // staging: wave w copies bytes [w*8KB, w*8KB+8KB) of the 32KB tile image
    const int lane16 = lane * 16;
    auto stage = [&](int t, char* buf) {
        const char* g = ((w < 2) ? kq0 : vq0) + (size_t)t * 16384 + (w & 1) * 8192 + lane16;
        char* d = buf + (w >> 1) * 16384 + (w & 1) * 8192;
        #pragma unroll
        for (int u = 0; u < 8; ++u)
            stage16(g + u * 1024, d + u * 1024, lane16);
    };

    stage(0, smem);
    __syncthreads();
    int cur = 0;

    #pragma unroll 1
    for (int t = 0; t < NT; ++t) {
        char* kb = smem + cur * 32768;
        char* vb = kb + 16384;
        if (t + 1 < NT) stage(t + 1, smem + (cur ^ 1) * 32768);   // prefetch

        // ---- E^T[j][i] = sum_c K[c,j] Q[c,i], j = crow|crow+32 ----
        f32x16 e0, e1;
        #pragma unroll
        for (int rr = 0; rr < 16; ++rr) { e0[rr] = 0.0f; e1[rr] = 0.0f; }
        {
            const char* kr0 = kb + l31 * 256;
            const int   kx  = l31 & 15;
            __builtin_amdgcn_s_setprio(1);
            #pragma unroll
            for (int ch = 0; ch < 8; ++ch) {
                const int off = ((2 * ch + h) ^ kx) << 4;
                bf16x8 k0 = __builtin_bit_cast(bf16x8, *(const i32x4*)(kr0 + off));
                e0 = __builtin_amdgcn_mfma_f32_32x32x16_bf16(k0, qf[ch], e0, 0, 0, 0);
                bf16x8 k1 = __builtin_bit_cast(bf16x8, *(const i32x4*)(kr0 + 8192 + off));
                e1 = __builtin_amdgcn_mfma_f32_32x32x16_bf16(k1, qf[ch], e1, 0, 0, 0);
            }
            __builtin_amdgcn_s_setprio(0);
        }

        // ---- online softmax (log2 domain; q pre-scaled by log2e) ----
        float a[8];
        #pragma unroll
        for (int i = 0; i < 8; ++i)
            a[i] = fmaxf(fmaxf(e0[2 * i], e0[2 * i + 1]),
                         fmaxf(e1[2 * i], e1[2 * i + 1]));
        float mt = fmaxf(fmaxf(fmaxf(a[0], a[1]), fmaxf(a[2], a[3])),
                         fmaxf(fmaxf(a[4], a[5]), fmaxf(a[6], a[7])));
        mt = fmaxf(mt, __shfl_xor(mt, 32, 64));
        if (!__all(mt <= m_run + 8.0f)) {      // defer-max (T13)
            const float mn = fmaxf(m_run, mt);
            const float sc = exp2f(m_run - mn);
            #pragma unroll
            for (int cb = 0; cb < 4; ++cb)
                #pragma unroll
                for (int rr = 0; rr < 16; ++rr) accO[cb][rr] *= sc;
            #pragma unroll
            for (int rr = 0; rr < 16; ++rr) ls[rr] *= sc;
            m_run = mn;
        }
        #pragma unroll
        for (int rr = 0; rr < 16; ++rr) {
            e0[rr] = exp2f(e0[rr] - m_run);
            e1[rr] = exp2f(e1[rr] - m_run);
        }

        // pack P: frag m element e <-> key 16m + (e&3) + 4h + 8*(e>>2)
        bf16x8 pf[4];
        #pragma unroll
        for (int m = 0; m < 4; ++m) {
            bf16x8 p;
            #pragma unroll
            for (int e = 0; e < 8; ++e)
                p[e] = (__bf16)((m < 2) ? e0[(m & 1) * 8 + e] : e1[(m & 1) * 8 + e]);
            pf[m] = p;
        }

        // ---- l += 1^T P (matrix pipe) ; accO += V P ----
        __builtin_amdgcn_s_setprio(1);
        #pragma unroll
        for (int m = 0; m < 4; ++m)
            ls = __builtin_amdgcn_mfma_f32_32x32x16_bf16(ones, pf[m], ls, 0, 0, 0);
        {
            const int rsw = l31 >> 1;          // (R & 15)
            const int ci  = (l31 & 1) * 8;
            #pragma unroll
            for (int cb = 0; cb < 4; ++cb) {
                const char* vrow = vb + (cb * 16 + (l31 >> 1)) * 256;
                #pragma unroll
                for (int m = 0; m < 4; ++m) {
                    bf16x8 vf = __builtin_bit_cast(bf16x8,
                        *(const i32x4*)(vrow + (((ci + 2 * m + h) ^ rsw) << 4)));
                    accO[cb] = __builtin_amdgcn_mfma_f32_32x32x16_bf16(
                        vf, pf[m], accO[cb], 0, 0, 0);
                }
            }
        }
        __builtin_amdgcn_s_setprio(0);

        __syncthreads();          // drains DMA (t+1 ready) + readers done
        cur ^= 1;
    }

    // ---- epilogue: un-normalized partial O (bf16) + per-query (M,L) ----
    const float l_run = ls[0];
    if (h == 0)
        mlG[((size_t)quarter * B_ + b) * N_ + i0 + l31] = make_float2(m_run, l_run);

    unsigned short* pOq = pO + ((size_t)quarter * B_ + b) * C_ * N_;
    #pragma unroll
    for (int cb = 0; cb < 4; ++cb) {
        #pragma unroll
        for (int rr = 0; rr < 16; ++rr) {
            const int c = cb * 32 + (rr & 3) + 8 * (rr >> 2) + 4 * h;
            pOq[(size_t)c * N_ + i0 + l31] =
                __builtin_bit_cast(unsigned short, (__bf16)accO[cb][rr]);
        }
    }
}

// ---------------- merge NS key-range partials + residual ----------------
template<int NS>
__global__ __launch_bounds__(256) void merge_kernel(
    const float* __restrict__ x,
    const unsigned short* __restrict__ pO,   // [NS][B][C][N] bf16
    const float2* __restrict__ mlG,          // [NS][B][N]
    float* __restrict__ out)
{
    const int idx = blockIdx.x * 256 + threadIdx.x;   // over B*C*N/4
    const int nq  = idx & (N_ / 4 - 1);
    const int bc  = idx >> 10;                        // b*C + c
    const int b   = bc >> 7;
    const size_t off = (size_t)bc * N_ + nq * 4;

    float4 xv = *(const float4*)(x + off);

    float2 ml[NS][4];
    #pragma unroll
    for (int q = 0; q < NS; ++q) {
        const float2* mp = mlG + ((size_t)q * B_ + b) * N_ + nq * 4;
        #pragma unroll
        for (int j = 0; j < 4; ++j) ml[q][j] = mp[j];
    }
    float M[4];
    #pragma unroll
    for (int j = 0; j < 4; ++j) {
        M[j] = ml[0][j].x;
        #pragma unroll
        for (int q = 1; q < NS; ++q) M[j] = fmaxf(M[j], ml[q][j].x);
    }
    float num[4] = {0, 0, 0, 0}, den[4] = {0, 0, 0, 0};
    #pragma unroll
    for (int q = 0; q < NS; ++q) {
        bf16x4 r = *(const bf16x4*)(pO + (size_t)q * B_ * C_ * N_ + off);
        #pragma unroll
        for (int j = 0; j < 4; ++j) {
            float wq = exp2f(ml[q][j].x - M[j]);
            num[j] += wq * (float)r[j];
            den[j] += wq * ml[q][j].y;
        }
    }
    float4 ov;
    ov.x = xv.x + num[0] / den[0];
    ov.y = xv.y + num[1] / den[1];
    ov.z = xv.z + num[2] / den[2];
    ov.w = xv.w + num[3] / den[3];
    *(float4*)(out + off) = ov;
}

extern "C" void kernel_launch(void* const* d_in, const int* in_sizes, int n_in,
                              void* d_out, int out_size, void* d_ws, size_t ws_size,
                              hipStream_t stream)
{
    const float* x  = (const float*)d_in[0];
    const float* Wq = (const float*)d_in[1];
    const float* bq = (const float*)d_in[2];
    const float* Wk = (const float*)d_in[3];
    const float* bk = (const float*)d_in[4];
    const float* Wv = (const float*)d_in[5];
    const float* bv = (const float*)d_in[6];
    float* out = (float*)d_out;

    unsigned short* qT = (unsigned short*)d_ws;              // 4 MiB
    char* kQ = (char*)(qT + (size_t)B_ * N_ * C_);           // 4 MiB
    char* vQ = kQ + (size_t)B_ * KB_PER_B;                   // 4 MiB
    unsigned short* pO = (unsigned short*)(vQ + (size_t)B_ * KB_PER_B);

    const size_t slotO  = (size_t)B_ * C_ * N_;              // bf16 elems / slot
    const size_t slotML = (size_t)B_ * N_;                   // float2 / slot
    const size_t need4  = 3ull * B_ * N_ * C_ * 2 + 4 * (slotO * 2 + slotML * 8);

    proj_kernel<<<384, 256, 0, stream>>>(x, Wq, bq, Wk, bk, Wv, bv, qT, kQ, vQ);

    if (ws_size >= need4) {
        float2* mlG = (float2*)(pO + 4 * slotO);
        attn_kernel<4><<<B_ * (N_ / 128) * 4, 256, 0, stream>>>(qT, kQ, vQ, pO, mlG);
        merge_kernel<4><<<(B_ * C_ * N_ / 4) / 256, 256, 0, stream>>>(x, pO, mlG, out);
    } else {
        float2* mlG = (float2*)(pO + 2 * slotO);
        attn_kernel<2><<<B_ * (N_ / 128) * 2, 256, 0, stream>>>(qT, kQ, vQ, pO, mlG);
        merge_kernel<2><<<(B_ * C_ * N_ / 4) / 256, 256, 0, stream>>>(x, pO, mlG, out);
    }
}